// Round 5
// baseline (37.201 us; speedup 1.0000x reference)
//
#include <hip/hip_runtime.h>

#define EPSV 1e-7f

// v7: occupancy doubling. Evidence chain: time tracks VALU inst count linearly
// (v6: -15% insts -> -17% time) at ~3.8x the pure-issue floor => stall-bound
// with thin occupancy. v6 peak live set ~150+ VGPR => 2 waves/SIMD (waves
// halve at 64/128/256). This version: 2 windows/thread + column factorization
// keeps peak live ~100 VGPR; __launch_bounds__(256,4) pins 4 waves/SIMD
// (v3's body proved this pin spill-free once its atomic tail is accounted).
// All loads 8B-aligned float2; no havef2 branch, no per-window predicate.
// Ending: v5's contention-free store + tiny reducer (atomics cost ~10us/1024).
__global__ __launch_bounds__(256, 4) void matting_loss_kernel(
    const float* __restrict__ outp, const float* __restrict__ cont,
    float* __restrict__ ws)
{
    const int H = 512, W = 512, NW = 510;
    const int HW = H * W;

    // --- XCD swizzle (bijective: 2048 % 8 == 0) ---
    const int lin = blockIdx.x + 8 * (blockIdx.y + 64 * blockIdx.z);
    const int swz = (lin & 7) * 256 + (lin >> 3);
    const int b   = swz >> 9;                       // image 0..3
    const int rem = swz & 511;
    const int gx  = (rem & 7) * 32 + threadIdx.x;   // 0..255 -> wx0 = 2*gx
    const int gy  = (rem >> 3) * 8 + threadIdx.y;   // 0..511 -> window row
    const int wx0 = gx * 2;
    const int wy  = gy;

    const float* Cin = cont + (size_t)b * 3 * HW;
    const float* Xin = outp + (size_t)b * 3 * HW;

    float contrib = 0.0f;
    const float inv9 = 1.0f / 9.0f;

    if (wy < NW && wx0 < NW) {     // wx0 <= 508 -> cols <= 511, windows wx0,wx0+1 valid
        const int base = wy * W + wx0;

        // Content pixels: 3 ch x 3 rows x 4 cols, two 8B-aligned float2 each.
        float Cb[3][3][4];
        #pragma unroll
        for (int ch = 0; ch < 3; ++ch)
            #pragma unroll
            for (int r = 0; r < 3; ++r) {
                const float* p = Cin + ch * HW + base + r * W;
                float2 v0 = *(const float2*)p;
                float2 v1 = *(const float2*)(p + 2);
                Cb[ch][r][0] = v0.x; Cb[ch][r][1] = v0.y;
                Cb[ch][r][2] = v1.x; Cb[ch][r][3] = v1.y;
            }

        // Hoist channel-0 X rows; latency hides under the moment phase.
        float Xc[3][4];
        #pragma unroll
        for (int r = 0; r < 3; ++r) {
            const float* p = Xin + base + r * W;
            float2 v0 = *(const float2*)p;
            float2 v1 = *(const float2*)(p + 2);
            Xc[r][0] = v0.x; Xc[r][1] = v0.y; Xc[r][2] = v1.x; Xc[r][3] = v1.y;
        }

        // --- Moment phase: per-column partial sums (computed once) ---
        float cI0[4], cI1[4], cI2[4];
        float c00[4], c01[4], c02[4], c11[4], c12[4], c22[4];
        #pragma unroll
        for (int j = 0; j < 4; ++j) {
            float a0 = Cb[0][0][j], a1 = Cb[0][1][j], a2 = Cb[0][2][j];
            float e0 = Cb[1][0][j], e1 = Cb[1][1][j], e2 = Cb[1][2][j];
            float d0 = Cb[2][0][j], d1 = Cb[2][1][j], d2 = Cb[2][2][j];
            cI0[j] = a0 + a1 + a2;
            cI1[j] = e0 + e1 + e2;
            cI2[j] = d0 + d1 + d2;
            c00[j] = a0 * a0 + a1 * a1 + a2 * a2;
            c01[j] = a0 * e0 + a1 * e1 + a2 * e2;
            c02[j] = a0 * d0 + a1 * d1 + a2 * d2;
            c11[j] = e0 * e0 + e1 * e1 + e2 * e2;
            c12[j] = e0 * d0 + e1 * d1 + e2 * d2;
            c22[j] = d0 * d0 + d1 * d1 + d2 * d2;
        }

        // Per-window: 3-column sums -> mu + closed-form symmetric 3x3 inverse.
        float mu[2][3], iv[2][6];
        #pragma unroll
        for (int w = 0; w < 2; ++w) {
            float sI0 = cI0[w] + cI0[w + 1] + cI0[w + 2];
            float sI1 = cI1[w] + cI1[w + 1] + cI1[w + 2];
            float sI2 = cI2[w] + cI2[w + 1] + cI2[w + 2];
            float s00 = c00[w] + c00[w + 1] + c00[w + 2];
            float s01 = c01[w] + c01[w + 1] + c01[w + 2];
            float s02 = c02[w] + c02[w + 1] + c02[w + 2];
            float s11 = c11[w] + c11[w + 1] + c11[w + 2];
            float s12 = c12[w] + c12[w + 1] + c12[w + 2];
            float s22 = c22[w] + c22[w + 1] + c22[w + 2];
            float m0 = sI0 * inv9, m1 = sI1 * inv9, m2 = sI2 * inv9;
            const float ed = EPSV * inv9;
            float v00 = s00 * inv9 - m0 * m0 + ed;
            float v01 = s01 * inv9 - m0 * m1;
            float v02 = s02 * inv9 - m0 * m2;
            float v11 = s11 * inv9 - m1 * m1 + ed;
            float v12 = s12 * inv9 - m1 * m2;
            float v22 = s22 * inv9 - m2 * m2 + ed;
            float k00 = v11 * v22 - v12 * v12;
            float k01 = v02 * v12 - v01 * v22;
            float k02 = v01 * v12 - v02 * v11;
            float det = v00 * k00 + v01 * k01 + v02 * k02;
            float id  = __builtin_amdgcn_rcpf(det);   // v_rcp_f32
            mu[w][0] = m0; mu[w][1] = m1; mu[w][2] = m2;
            iv[w][0] = k00 * id; iv[w][1] = k01 * id; iv[w][2] = k02 * id;
            iv[w][3] = (v00 * v22 - v02 * v02) * id;
            iv[w][4] = (v01 * v02 - v00 * v12) * id;
            iv[w][5] = (v00 * v11 - v01 * v01) * id;
        }

        // --- X phase: per-column partials distributed into window accums ---
        #pragma unroll
        for (int c = 0; c < 3; ++c) {
            if (c > 0) {
                #pragma unroll
                for (int r = 0; r < 3; ++r) {
                    const float* p = Xin + c * HW + base + r * W;
                    float2 v0 = *(const float2*)p;
                    float2 v1 = *(const float2*)(p + 2);
                    Xc[r][0] = v0.x; Xc[r][1] = v0.y;
                    Xc[r][2] = v1.x; Xc[r][3] = v1.y;
                }
            }
            float S[2]  = {0, 0};
            float SS[2] = {0, 0};
            float W0[2] = {0, 0};
            float W1[2] = {0, 0};
            float W2[2] = {0, 0};
            #pragma unroll
            for (int j = 0; j < 4; ++j) {
                float x0 = Xc[0][j], x1 = Xc[1][j], x2 = Xc[2][j];
                float cS  = x0 + x1 + x2;
                float cSS = x0 * x0 + x1 * x1 + x2 * x2;
                float cW0 = x0 * Cb[0][0][j] + x1 * Cb[0][1][j] + x2 * Cb[0][2][j];
                float cW1 = x0 * Cb[1][0][j] + x1 * Cb[1][1][j] + x2 * Cb[1][2][j];
                float cW2 = x0 * Cb[2][0][j] + x1 * Cb[2][1][j] + x2 * Cb[2][2][j];
                #pragma unroll
                for (int w = 0; w < 2; ++w)
                    if (w <= j && j <= w + 2) {   // compile-time predicate
                        S[w] += cS; SS[w] += cSS;
                        W0[w] += cW0; W1[w] += cW1; W2[w] += cW2;
                    }
            }
            #pragma unroll
            for (int w = 0; w < 2; ++w) {
                float u0 = W0[w] - S[w] * mu[w][0];
                float u1 = W1[w] - S[w] * mu[w][1];
                float u2 = W2[w] - S[w] * mu[w][2];
                float q = u0 * (iv[w][0] * u0 + iv[w][1] * u1 + iv[w][2] * u2)
                        + u1 * (iv[w][1] * u0 + iv[w][3] * u1 + iv[w][4] * u2)
                        + u2 * (iv[w][2] * u0 + iv[w][4] * u1 + iv[w][5] * u2);
                contrib += SS[w] - (S[w] * S[w] + q) * inv9;  // all windows valid
            }
        }
    }

    // Wave shuffle reduction -> cross-wave LDS -> ONE plain store per block.
    #pragma unroll
    for (int off = 32; off > 0; off >>= 1)
        contrib += __shfl_down(contrib, off, 64);

    __shared__ float wsum[4];
    const int tid = threadIdx.y * 32 + threadIdx.x;
    const int lane = tid & 63, wv = tid >> 6;
    if (lane == 0) wsum[wv] = contrib;
    __syncthreads();
    if (tid == 0)
        ws[swz] = wsum[0] + wsum[1] + wsum[2] + wsum[3];
}

// Tiny reducer: image b owns ws[b*512 .. b*512+511]. Writes loss[b] directly.
__global__ __launch_bounds__(256) void reduce_kernel(
    const float* __restrict__ ws, float* __restrict__ loss)
{
    const int b = blockIdx.x;
    const int t = threadIdx.x;
    float v = ws[b * 512 + t] + ws[b * 512 + 256 + t];
    #pragma unroll
    for (int off = 32; off > 0; off >>= 1)
        v += __shfl_down(v, off, 64);

    __shared__ float s[4];
    if ((t & 63) == 0) s[t >> 6] = v;
    __syncthreads();
    if (t == 0) loss[b] = s[0] + s[1] + s[2] + s[3];
}

extern "C" void kernel_launch(void* const* d_in, const int* in_sizes, int n_in,
                              void* d_out, int out_size, void* d_ws, size_t ws_size,
                              hipStream_t stream) {
    const float* outp = (const float*)d_in[0];   // output: (4,3,512,512) f32
    const float* cont = (const float*)d_in[1];   // content: (4,3,512,512) f32
    float* loss = (float*)d_out;                 // (4,1,1) f32
    float* ws   = (float*)d_ws;                  // 2048 floats of workspace

    dim3 block(32, 8, 1);
    dim3 grid(8, 64, 4);   // 256 thread-cols x 512 thread-rows x 4 images
    matting_loss_kernel<<<grid, block, 0, stream>>>(outp, cont, ws);
    reduce_kernel<<<dim3(4, 1, 1), dim3(256, 1, 1), 0, stream>>>(ws, loss);
}

// Round 6
// 17.417 us; speedup vs baseline: 2.1359x; 2.1359x over previous
//
#include <hip/hip_runtime.h>

#define EPSV 1e-7f

// v8: v7 with the launch_bounds pin REMOVED -- the only change.
// R5 evidence (first direct counters): __launch_bounds__(256,4) clamped the
// allocator to VGPR=64 and spilled ~33 floats/thread (WRITE_SIZE=69MB on a
// kernel that legitimately writes 8KB; FETCH 46MB vs 25MB compulsory).
// Same pathology poisoned v3. The 2-window body's true live set is ~100 VGPR;
// unpinned it should land in the 65-128 tier -> 4 waves/SIMD, no spills.
// This is the clean occupancy-doubling experiment vs v6 (17.6us, 2 waves/SIMD
// at ~150 VGPR). Pre-committed read: ~10-13us main => occupancy was binding;
// ~17us with VGPR<=128 => latency-bound, LDS staging next; VGPR>128 => trim.
__global__ __launch_bounds__(256) void matting_loss_kernel(
    const float* __restrict__ outp, const float* __restrict__ cont,
    float* __restrict__ ws)
{
    const int H = 512, W = 512, NW = 510;
    const int HW = H * W;

    // --- XCD swizzle (bijective: 2048 % 8 == 0) ---
    const int lin = blockIdx.x + 8 * (blockIdx.y + 64 * blockIdx.z);
    const int swz = (lin & 7) * 256 + (lin >> 3);
    const int b   = swz >> 9;                       // image 0..3
    const int rem = swz & 511;
    const int gx  = (rem & 7) * 32 + threadIdx.x;   // 0..255 -> wx0 = 2*gx
    const int gy  = (rem >> 3) * 8 + threadIdx.y;   // 0..511 -> window row
    const int wx0 = gx * 2;
    const int wy  = gy;

    const float* Cin = cont + (size_t)b * 3 * HW;
    const float* Xin = outp + (size_t)b * 3 * HW;

    float contrib = 0.0f;
    const float inv9 = 1.0f / 9.0f;

    if (wy < NW && wx0 < NW) {     // wx0 <= 508 -> cols <= 511, windows wx0,wx0+1 valid
        const int base = wy * W + wx0;

        // Content pixels: 3 ch x 3 rows x 4 cols, two 8B-aligned float2 each.
        float Cb[3][3][4];
        #pragma unroll
        for (int ch = 0; ch < 3; ++ch)
            #pragma unroll
            for (int r = 0; r < 3; ++r) {
                const float* p = Cin + ch * HW + base + r * W;
                float2 v0 = *(const float2*)p;
                float2 v1 = *(const float2*)(p + 2);
                Cb[ch][r][0] = v0.x; Cb[ch][r][1] = v0.y;
                Cb[ch][r][2] = v1.x; Cb[ch][r][3] = v1.y;
            }

        // Hoist channel-0 X rows; latency hides under the moment phase.
        float Xc[3][4];
        #pragma unroll
        for (int r = 0; r < 3; ++r) {
            const float* p = Xin + base + r * W;
            float2 v0 = *(const float2*)p;
            float2 v1 = *(const float2*)(p + 2);
            Xc[r][0] = v0.x; Xc[r][1] = v0.y; Xc[r][2] = v1.x; Xc[r][3] = v1.y;
        }

        // --- Moment phase: per-column partial sums (computed once) ---
        float cI0[4], cI1[4], cI2[4];
        float c00[4], c01[4], c02[4], c11[4], c12[4], c22[4];
        #pragma unroll
        for (int j = 0; j < 4; ++j) {
            float a0 = Cb[0][0][j], a1 = Cb[0][1][j], a2 = Cb[0][2][j];
            float e0 = Cb[1][0][j], e1 = Cb[1][1][j], e2 = Cb[1][2][j];
            float d0 = Cb[2][0][j], d1 = Cb[2][1][j], d2 = Cb[2][2][j];
            cI0[j] = a0 + a1 + a2;
            cI1[j] = e0 + e1 + e2;
            cI2[j] = d0 + d1 + d2;
            c00[j] = a0 * a0 + a1 * a1 + a2 * a2;
            c01[j] = a0 * e0 + a1 * e1 + a2 * e2;
            c02[j] = a0 * d0 + a1 * d1 + a2 * d2;
            c11[j] = e0 * e0 + e1 * e1 + e2 * e2;
            c12[j] = e0 * d0 + e1 * d1 + e2 * d2;
            c22[j] = d0 * d0 + d1 * d1 + d2 * d2;
        }

        // Per-window: 3-column sums -> mu + closed-form symmetric 3x3 inverse.
        float mu[2][3], iv[2][6];
        #pragma unroll
        for (int w = 0; w < 2; ++w) {
            float sI0 = cI0[w] + cI0[w + 1] + cI0[w + 2];
            float sI1 = cI1[w] + cI1[w + 1] + cI1[w + 2];
            float sI2 = cI2[w] + cI2[w + 1] + cI2[w + 2];
            float s00 = c00[w] + c00[w + 1] + c00[w + 2];
            float s01 = c01[w] + c01[w + 1] + c01[w + 2];
            float s02 = c02[w] + c02[w + 1] + c02[w + 2];
            float s11 = c11[w] + c11[w + 1] + c11[w + 2];
            float s12 = c12[w] + c12[w + 1] + c12[w + 2];
            float s22 = c22[w] + c22[w + 1] + c22[w + 2];
            float m0 = sI0 * inv9, m1 = sI1 * inv9, m2 = sI2 * inv9;
            const float ed = EPSV * inv9;
            float v00 = s00 * inv9 - m0 * m0 + ed;
            float v01 = s01 * inv9 - m0 * m1;
            float v02 = s02 * inv9 - m0 * m2;
            float v11 = s11 * inv9 - m1 * m1 + ed;
            float v12 = s12 * inv9 - m1 * m2;
            float v22 = s22 * inv9 - m2 * m2 + ed;
            float k00 = v11 * v22 - v12 * v12;
            float k01 = v02 * v12 - v01 * v22;
            float k02 = v01 * v12 - v02 * v11;
            float det = v00 * k00 + v01 * k01 + v02 * k02;
            float id  = __builtin_amdgcn_rcpf(det);   // v_rcp_f32
            mu[w][0] = m0; mu[w][1] = m1; mu[w][2] = m2;
            iv[w][0] = k00 * id; iv[w][1] = k01 * id; iv[w][2] = k02 * id;
            iv[w][3] = (v00 * v22 - v02 * v02) * id;
            iv[w][4] = (v01 * v02 - v00 * v12) * id;
            iv[w][5] = (v00 * v11 - v01 * v01) * id;
        }

        // --- X phase: per-column partials distributed into window accums ---
        #pragma unroll
        for (int c = 0; c < 3; ++c) {
            if (c > 0) {
                #pragma unroll
                for (int r = 0; r < 3; ++r) {
                    const float* p = Xin + c * HW + base + r * W;
                    float2 v0 = *(const float2*)p;
                    float2 v1 = *(const float2*)(p + 2);
                    Xc[r][0] = v0.x; Xc[r][1] = v0.y;
                    Xc[r][2] = v1.x; Xc[r][3] = v1.y;
                }
            }
            float S[2]  = {0, 0};
            float SS[2] = {0, 0};
            float W0[2] = {0, 0};
            float W1[2] = {0, 0};
            float W2[2] = {0, 0};
            #pragma unroll
            for (int j = 0; j < 4; ++j) {
                float x0 = Xc[0][j], x1 = Xc[1][j], x2 = Xc[2][j];
                float cS  = x0 + x1 + x2;
                float cSS = x0 * x0 + x1 * x1 + x2 * x2;
                float cW0 = x0 * Cb[0][0][j] + x1 * Cb[0][1][j] + x2 * Cb[0][2][j];
                float cW1 = x0 * Cb[1][0][j] + x1 * Cb[1][1][j] + x2 * Cb[1][2][j];
                float cW2 = x0 * Cb[2][0][j] + x1 * Cb[2][1][j] + x2 * Cb[2][2][j];
                #pragma unroll
                for (int w = 0; w < 2; ++w)
                    if (w <= j && j <= w + 2) {   // compile-time predicate
                        S[w] += cS; SS[w] += cSS;
                        W0[w] += cW0; W1[w] += cW1; W2[w] += cW2;
                    }
            }
            #pragma unroll
            for (int w = 0; w < 2; ++w) {
                float u0 = W0[w] - S[w] * mu[w][0];
                float u1 = W1[w] - S[w] * mu[w][1];
                float u2 = W2[w] - S[w] * mu[w][2];
                float q = u0 * (iv[w][0] * u0 + iv[w][1] * u1 + iv[w][2] * u2)
                        + u1 * (iv[w][1] * u0 + iv[w][3] * u1 + iv[w][4] * u2)
                        + u2 * (iv[w][2] * u0 + iv[w][4] * u1 + iv[w][5] * u2);
                contrib += SS[w] - (S[w] * S[w] + q) * inv9;  // all windows valid
            }
        }
    }

    // Wave shuffle reduction -> cross-wave LDS -> ONE plain store per block.
    #pragma unroll
    for (int off = 32; off > 0; off >>= 1)
        contrib += __shfl_down(contrib, off, 64);

    __shared__ float wsum[4];
    const int tid = threadIdx.y * 32 + threadIdx.x;
    const int lane = tid & 63, wv = tid >> 6;
    if (lane == 0) wsum[wv] = contrib;
    __syncthreads();
    if (tid == 0)
        ws[swz] = wsum[0] + wsum[1] + wsum[2] + wsum[3];
}

// Tiny reducer: image b owns ws[b*512 .. b*512+511]. Writes loss[b] directly.
__global__ __launch_bounds__(256) void reduce_kernel(
    const float* __restrict__ ws, float* __restrict__ loss)
{
    const int b = blockIdx.x;
    const int t = threadIdx.x;
    float v = ws[b * 512 + t] + ws[b * 512 + 256 + t];
    #pragma unroll
    for (int off = 32; off > 0; off >>= 1)
        v += __shfl_down(v, off, 64);

    __shared__ float s[4];
    if ((t & 63) == 0) s[t >> 6] = v;
    __syncthreads();
    if (t == 0) loss[b] = s[0] + s[1] + s[2] + s[3];
}

extern "C" void kernel_launch(void* const* d_in, const int* in_sizes, int n_in,
                              void* d_out, int out_size, void* d_ws, size_t ws_size,
                              hipStream_t stream) {
    const float* outp = (const float*)d_in[0];   // output: (4,3,512,512) f32
    const float* cont = (const float*)d_in[1];   // content: (4,3,512,512) f32
    float* loss = (float*)d_out;                 // (4,1,1) f32
    float* ws   = (float*)d_ws;                  // 2048 floats of workspace

    dim3 block(32, 8, 1);
    dim3 grid(8, 64, 4);   // 256 thread-cols x 512 thread-rows x 4 images
    matting_loss_kernel<<<grid, block, 0, stream>>>(outp, cont, ws);
    reduce_kernel<<<dim3(4, 1, 1), dim3(256, 1, 1), 0, stream>>>(ws, loss);
}

// Round 7
// 14.668 us; speedup vs baseline: 2.5362x; 1.1874x over previous
//
#include <hip/hip_runtime.h>

#define EPSV 1e-7f

// v9: packed-FP32 rewrite. v6 (4-win, ~1360 inst/thd, 2 waves/SIMD) == v8
// (2-win, ~800 inst/thd, 4 waves/SIMD) == ~17.5us: occupancy gain exactly
// cancelled the inst overhead; both sit ~3x above the ~5us pure-issue floor.
// Lever that cuts insts WITHOUT adding registers: v_pk_fma_f32 (CDNA VOP3P,
// 2 f32 ops/inst) via clang ext_vector_type(2) -> <2 x float>. Columns pack
// as 2 pairs, the 2 windows pack as one pair ({w0,w1} = P01+{P01.y,P23.x}+P23).
// ~800 -> ~450 inst/thread. Also: ALL 18 X loads hoisted to kernel start
// (one burst, latency under the whole moment phase; X phase load-free).
// Peak live ~118 VGPR -> stays in the <=128 / 4-waves-per-SIMD tier.
// Pre-committed: 12.5-14.5us => issue-bound confirmed; neutral => compiler
// already packed / latency-bound, go disasm+LDS; regression => VGPR>128.
typedef float f2 __attribute__((ext_vector_type(2)));

__global__ __launch_bounds__(256) void matting_loss_kernel(
    const float* __restrict__ outp, const float* __restrict__ cont,
    float* __restrict__ ws)
{
    const int H = 512, W = 512, NW = 510;
    const int HW = H * W;

    // --- XCD swizzle (bijective: 2048 % 8 == 0) ---
    const int lin = blockIdx.x + 8 * (blockIdx.y + 64 * blockIdx.z);
    const int swz = (lin & 7) * 256 + (lin >> 3);
    const int b   = swz >> 9;                       // image 0..3
    const int rem = swz & 511;
    const int gx  = (rem & 7) * 32 + threadIdx.x;   // 0..255 -> wx0 = 2*gx
    const int gy  = (rem >> 3) * 8 + threadIdx.y;   // 0..511 -> window row
    const int wx0 = gx * 2;
    const int wy  = gy;

    const float* Cin = cont + (size_t)b * 3 * HW;
    const float* Xin = outp + (size_t)b * 3 * HW;

    float contrib = 0.0f;
    const float inv9 = 1.0f / 9.0f;

    if (wy < NW && wx0 < NW) {     // wx0 <= 508: windows wx0, wx0+1 both valid
        const int base = wy * W + wx0;

        // One load burst: 18 C + 18 X f2 loads, all in flight together.
        f2 Cb[3][3][2];   // [ch][row][colpair] : {cols 0,1} and {cols 2,3}
        f2 Xb[3][3][2];
        #pragma unroll
        for (int ch = 0; ch < 3; ++ch)
            #pragma unroll
            for (int r = 0; r < 3; ++r) {
                const float* p = Cin + ch * HW + base + r * W;
                Cb[ch][r][0] = *(const f2*)p;
                Cb[ch][r][1] = *(const f2*)(p + 2);
                const float* q = Xin + ch * HW + base + r * W;
                Xb[ch][r][0] = *(const f2*)q;
                Xb[ch][r][1] = *(const f2*)(q + 2);
            }

        // --- Moment phase: packed per-column-pair partial sums ---
        f2 cI0[2], cI1[2], cI2[2];
        f2 c00[2], c01[2], c02[2], c11[2], c12[2], c22[2];
        #pragma unroll
        for (int p = 0; p < 2; ++p) {
            f2 a0 = Cb[0][0][p], a1 = Cb[0][1][p], a2 = Cb[0][2][p];
            f2 e0 = Cb[1][0][p], e1 = Cb[1][1][p], e2 = Cb[1][2][p];
            f2 d0 = Cb[2][0][p], d1 = Cb[2][1][p], d2 = Cb[2][2][p];
            cI0[p] = a0 + a1 + a2;
            cI1[p] = e0 + e1 + e2;
            cI2[p] = d0 + d1 + d2;
            c00[p] = a0 * a0 + a1 * a1 + a2 * a2;
            c01[p] = a0 * e0 + a1 * e1 + a2 * e2;
            c02[p] = a0 * d0 + a1 * d1 + a2 * d2;
            c11[p] = e0 * e0 + e1 * e1 + e2 * e2;
            c12[p] = e0 * d0 + e1 * d1 + e2 * d2;
            c22[p] = d0 * d0 + d1 * d1 + d2 * d2;
        }

        // Window-pair sums: lane0 = window wx0 (cols 0+1+2),
        //                   lane1 = window wx0+1 (cols 1+2+3).
        #define WSUM(A) (A[0] + (f2){A[0].y, A[1].x} + A[1])
        f2 sI0 = WSUM(cI0), sI1 = WSUM(cI1), sI2 = WSUM(cI2);
        f2 s00 = WSUM(c00), s01 = WSUM(c01), s02 = WSUM(c02);
        f2 s11 = WSUM(c11), s12 = WSUM(c12), s22 = WSUM(c22);

        // Packed mu + closed-form symmetric 3x3 inverse (both windows at once).
        f2 mu0 = sI0 * inv9, mu1 = sI1 * inv9, mu2 = sI2 * inv9;
        const float ed = EPSV * inv9;
        f2 v00 = s00 * inv9 - mu0 * mu0 + ed;
        f2 v01 = s01 * inv9 - mu0 * mu1;
        f2 v02 = s02 * inv9 - mu0 * mu2;
        f2 v11 = s11 * inv9 - mu1 * mu1 + ed;
        f2 v12 = s12 * inv9 - mu1 * mu2;
        f2 v22 = s22 * inv9 - mu2 * mu2 + ed;
        f2 k00 = v11 * v22 - v12 * v12;
        f2 k01 = v02 * v12 - v01 * v22;
        f2 k02 = v01 * v12 - v02 * v11;
        f2 det = v00 * k00 + v01 * k01 + v02 * k02;
        f2 id;
        id.x = __builtin_amdgcn_rcpf(det.x);   // v_rcp_f32 (validated v3..v8)
        id.y = __builtin_amdgcn_rcpf(det.y);
        f2 iv0 = k00 * id, iv1 = k01 * id, iv2 = k02 * id;
        f2 iv3 = (v00 * v22 - v02 * v02) * id;
        f2 iv4 = (v01 * v02 - v00 * v12) * id;
        f2 iv5 = (v00 * v11 - v01 * v01) * id;

        // --- X phase: packed column-pair partials -> packed window quadratic ---
        #pragma unroll
        for (int c = 0; c < 3; ++c) {
            f2 cS[2], cSS[2], cW0[2], cW1[2], cW2[2];
            #pragma unroll
            for (int p = 0; p < 2; ++p) {
                f2 x0 = Xb[c][0][p], x1 = Xb[c][1][p], x2 = Xb[c][2][p];
                cS[p]  = x0 + x1 + x2;
                cSS[p] = x0 * x0 + x1 * x1 + x2 * x2;
                cW0[p] = x0 * Cb[0][0][p] + x1 * Cb[0][1][p] + x2 * Cb[0][2][p];
                cW1[p] = x0 * Cb[1][0][p] + x1 * Cb[1][1][p] + x2 * Cb[1][2][p];
                cW2[p] = x0 * Cb[2][0][p] + x1 * Cb[2][1][p] + x2 * Cb[2][2][p];
            }
            f2 S  = WSUM(cS),  SSw = WSUM(cSS);
            f2 W0 = WSUM(cW0), W1  = WSUM(cW1), W2 = WSUM(cW2);
            f2 u0 = W0 - S * mu0;
            f2 u1 = W1 - S * mu1;
            f2 u2 = W2 - S * mu2;
            f2 q = u0 * (iv0 * u0 + iv1 * u1 + iv2 * u2)
                 + u1 * (iv1 * u0 + iv3 * u1 + iv4 * u2)
                 + u2 * (iv2 * u0 + iv4 * u1 + iv5 * u2);
            f2 term = SSw - (S * S + q) * inv9;
            contrib += term.x + term.y;           // both windows valid
        }
        #undef WSUM
    }

    // Wave shuffle reduction -> cross-wave LDS -> ONE plain store per block.
    #pragma unroll
    for (int off = 32; off > 0; off >>= 1)
        contrib += __shfl_down(contrib, off, 64);

    __shared__ float wsum[4];
    const int tid = threadIdx.y * 32 + threadIdx.x;
    const int lane = tid & 63, wv = tid >> 6;
    if (lane == 0) wsum[wv] = contrib;
    __syncthreads();
    if (tid == 0)
        ws[swz] = wsum[0] + wsum[1] + wsum[2] + wsum[3];
}

// Tiny reducer: image b owns ws[b*512 .. b*512+511]. Writes loss[b] directly.
__global__ __launch_bounds__(256) void reduce_kernel(
    const float* __restrict__ ws, float* __restrict__ loss)
{
    const int b = blockIdx.x;
    const int t = threadIdx.x;
    float v = ws[b * 512 + t] + ws[b * 512 + 256 + t];
    #pragma unroll
    for (int off = 32; off > 0; off >>= 1)
        v += __shfl_down(v, off, 64);

    __shared__ float s[4];
    if ((t & 63) == 0) s[t >> 6] = v;
    __syncthreads();
    if (t == 0) loss[b] = s[0] + s[1] + s[2] + s[3];
}

extern "C" void kernel_launch(void* const* d_in, const int* in_sizes, int n_in,
                              void* d_out, int out_size, void* d_ws, size_t ws_size,
                              hipStream_t stream) {
    const float* outp = (const float*)d_in[0];   // output: (4,3,512,512) f32
    const float* cont = (const float*)d_in[1];   // content: (4,3,512,512) f32
    float* loss = (float*)d_out;                 // (4,1,1) f32
    float* ws   = (float*)d_ws;                  // 2048 floats of workspace

    dim3 block(32, 8, 1);
    dim3 grid(8, 64, 4);   // 256 thread-cols x 512 thread-rows x 4 images
    matting_loss_kernel<<<grid, block, 0, stream>>>(outp, cont, ws);
    reduce_kernel<<<dim3(4, 1, 1), dim3(256, 1, 1), 0, stream>>>(ws, loss);
}

// Round 8
// 14.526 us; speedup vs baseline: 2.5610x; 1.0097x over previous
//
#include <hip/hip_runtime.h>

#define EPSV 1e-7f

// v10: lane-op diet on v9 (14.7us). Model: CDNA4 v_pk_f32 is issue-relief only
// (FP32 peak 157.3 TF == scalar SIMD-32 rate), so the kernel is VALU-lane-op
// bound; floors: VALU ~5us, memory 25MB ~4us (overlapped), dispatch ~2-3us.
// Changes, all deterministic:
//  1. WSUM = T=A0+A1 (packed) + 2 scalar adds -- kills the misaligned-pair
//     movs of {A0.y,A1.x} (v_pk operands need aligned pairs). 24 sites.
//  2. adjugate kept unnormalized; q *= id once per channel (-3 packed muls).
//  3. packed f2 term accumulator across channels, single unpack at end.
// Kept: 2-win/thread, col-pair factorization, X-hoist burst, v_rcp_f32,
// XCD swizzle, contention-free store + tiny reducer (v5 win).
typedef float f2 __attribute__((ext_vector_type(2)));

__global__ __launch_bounds__(256) void matting_loss_kernel(
    const float* __restrict__ outp, const float* __restrict__ cont,
    float* __restrict__ ws)
{
    const int H = 512, W = 512, NW = 510;
    const int HW = H * W;

    // --- XCD swizzle (bijective: 2048 % 8 == 0) ---
    const int lin = blockIdx.x + 8 * (blockIdx.y + 64 * blockIdx.z);
    const int swz = (lin & 7) * 256 + (lin >> 3);
    const int b   = swz >> 9;                       // image 0..3
    const int rem = swz & 511;
    const int gx  = (rem & 7) * 32 + threadIdx.x;   // 0..255 -> wx0 = 2*gx
    const int gy  = (rem >> 3) * 8 + threadIdx.y;   // 0..511 -> window row
    const int wx0 = gx * 2;
    const int wy  = gy;

    const float* Cin = cont + (size_t)b * 3 * HW;
    const float* Xin = outp + (size_t)b * 3 * HW;

    float contrib = 0.0f;
    const float inv9 = 1.0f / 9.0f;

    // {w0,w1} window sums from column-pair partials P01={c0,c1}, P23={c2,c3}:
    // w0=c0+c1+c2, w1=c1+c2+c3. T=P01+P23 packed, then 2 scalar adds (no
    // misaligned-pair repack movs).
#define WSUM(OUT, A0, A1) { f2 T_ = (A0) + (A1); (OUT).x = T_.x + (A0).y; (OUT).y = T_.y + (A1).x; }

    if (wy < NW && wx0 < NW) {     // wx0 <= 508: windows wx0, wx0+1 both valid
        const int base = wy * W + wx0;

        // One load burst: 18 C + 18 X f2 loads, all in flight together.
        f2 Cb[3][3][2];   // [ch][row][colpair] : {cols 0,1} and {cols 2,3}
        f2 Xb[3][3][2];
        #pragma unroll
        for (int ch = 0; ch < 3; ++ch)
            #pragma unroll
            for (int r = 0; r < 3; ++r) {
                const float* p = Cin + ch * HW + base + r * W;
                Cb[ch][r][0] = *(const f2*)p;
                Cb[ch][r][1] = *(const f2*)(p + 2);
                const float* q = Xin + ch * HW + base + r * W;
                Xb[ch][r][0] = *(const f2*)q;
                Xb[ch][r][1] = *(const f2*)(q + 2);
            }

        // --- Moment phase: packed per-column-pair partial sums ---
        f2 cI0[2], cI1[2], cI2[2];
        f2 c00[2], c01[2], c02[2], c11[2], c12[2], c22[2];
        #pragma unroll
        for (int p = 0; p < 2; ++p) {
            f2 a0 = Cb[0][0][p], a1 = Cb[0][1][p], a2 = Cb[0][2][p];
            f2 e0 = Cb[1][0][p], e1 = Cb[1][1][p], e2 = Cb[1][2][p];
            f2 d0 = Cb[2][0][p], d1 = Cb[2][1][p], d2 = Cb[2][2][p];
            cI0[p] = a0 + a1 + a2;
            cI1[p] = e0 + e1 + e2;
            cI2[p] = d0 + d1 + d2;
            c00[p] = a0 * a0 + a1 * a1 + a2 * a2;
            c01[p] = a0 * e0 + a1 * e1 + a2 * e2;
            c02[p] = a0 * d0 + a1 * d1 + a2 * d2;
            c11[p] = e0 * e0 + e1 * e1 + e2 * e2;
            c12[p] = e0 * d0 + e1 * d1 + e2 * d2;
            c22[p] = d0 * d0 + d1 * d1 + d2 * d2;
        }

        f2 sI0, sI1, sI2, s00, s01, s02, s11, s12, s22;
        WSUM(sI0, cI0[0], cI0[1]); WSUM(sI1, cI1[0], cI1[1]); WSUM(sI2, cI2[0], cI2[1]);
        WSUM(s00, c00[0], c00[1]); WSUM(s01, c01[0], c01[1]); WSUM(s02, c02[0], c02[1]);
        WSUM(s11, c11[0], c11[1]); WSUM(s12, c12[0], c12[1]); WSUM(s22, c22[0], c22[1]);

        // Packed mu + adjugate of the regularized covariance (both windows).
        f2 mu0 = sI0 * inv9, mu1 = sI1 * inv9, mu2 = sI2 * inv9;
        const float ed = EPSV * inv9;
        f2 v00 = s00 * inv9 - mu0 * mu0 + ed;
        f2 v01 = s01 * inv9 - mu0 * mu1;
        f2 v02 = s02 * inv9 - mu0 * mu2;
        f2 v11 = s11 * inv9 - mu1 * mu1 + ed;
        f2 v12 = s12 * inv9 - mu1 * mu2;
        f2 v22 = s22 * inv9 - mu2 * mu2 + ed;
        f2 adj0 = v11 * v22 - v12 * v12;   // adj00
        f2 adj1 = v02 * v12 - v01 * v22;   // adj01
        f2 adj2 = v01 * v12 - v02 * v11;   // adj02
        f2 adj3 = v00 * v22 - v02 * v02;   // adj11
        f2 adj4 = v01 * v02 - v00 * v12;   // adj12
        f2 adj5 = v00 * v11 - v01 * v01;   // adj22
        f2 det = v00 * adj0 + v01 * adj1 + v02 * adj2;
        f2 id;
        id.x = __builtin_amdgcn_rcpf(det.x);   // v_rcp_f32 (validated v3..v9)
        id.y = __builtin_amdgcn_rcpf(det.y);

        // --- X phase: packed column-pair partials -> packed window quadratic ---
        f2 termAcc = (f2){0.0f, 0.0f};
        #pragma unroll
        for (int c = 0; c < 3; ++c) {
            f2 cS[2], cSS[2], cW0[2], cW1[2], cW2[2];
            #pragma unroll
            for (int p = 0; p < 2; ++p) {
                f2 x0 = Xb[c][0][p], x1 = Xb[c][1][p], x2 = Xb[c][2][p];
                cS[p]  = x0 + x1 + x2;
                cSS[p] = x0 * x0 + x1 * x1 + x2 * x2;
                cW0[p] = x0 * Cb[0][0][p] + x1 * Cb[0][1][p] + x2 * Cb[0][2][p];
                cW1[p] = x0 * Cb[1][0][p] + x1 * Cb[1][1][p] + x2 * Cb[1][2][p];
                cW2[p] = x0 * Cb[2][0][p] + x1 * Cb[2][1][p] + x2 * Cb[2][2][p];
            }
            f2 S, SSw, W0, W1, W2;
            WSUM(S,  cS[0],  cS[1]);  WSUM(SSw, cSS[0], cSS[1]);
            WSUM(W0, cW0[0], cW0[1]); WSUM(W1,  cW1[0], cW1[1]); WSUM(W2, cW2[0], cW2[1]);
            f2 u0 = W0 - S * mu0;
            f2 u1 = W1 - S * mu1;
            f2 u2 = W2 - S * mu2;
            f2 qa = u0 * (adj0 * u0 + adj1 * u1 + adj2 * u2)
                  + u1 * (adj1 * u0 + adj3 * u1 + adj4 * u2)
                  + u2 * (adj2 * u0 + adj4 * u1 + adj5 * u2);
            termAcc += SSw - (S * S + qa * id) * inv9;
        }
        contrib = termAcc.x + termAcc.y;       // both windows valid
    }
#undef WSUM

    // Wave shuffle reduction -> cross-wave LDS -> ONE plain store per block.
    #pragma unroll
    for (int off = 32; off > 0; off >>= 1)
        contrib += __shfl_down(contrib, off, 64);

    __shared__ float wsum[4];
    const int tid = threadIdx.y * 32 + threadIdx.x;
    const int lane = tid & 63, wv = tid >> 6;
    if (lane == 0) wsum[wv] = contrib;
    __syncthreads();
    if (tid == 0)
        ws[swz] = wsum[0] + wsum[1] + wsum[2] + wsum[3];
}

// Tiny reducer: image b owns ws[b*512 .. b*512+511]. Writes loss[b] directly.
__global__ __launch_bounds__(256) void reduce_kernel(
    const float* __restrict__ ws, float* __restrict__ loss)
{
    const int b = blockIdx.x;
    const int t = threadIdx.x;
    float v = ws[b * 512 + t] + ws[b * 512 + 256 + t];
    #pragma unroll
    for (int off = 32; off > 0; off >>= 1)
        v += __shfl_down(v, off, 64);

    __shared__ float s[4];
    if ((t & 63) == 0) s[t >> 6] = v;
    __syncthreads();
    if (t == 0) loss[b] = s[0] + s[1] + s[2] + s[3];
}

extern "C" void kernel_launch(void* const* d_in, const int* in_sizes, int n_in,
                              void* d_out, int out_size, void* d_ws, size_t ws_size,
                              hipStream_t stream) {
    const float* outp = (const float*)d_in[0];   // output: (4,3,512,512) f32
    const float* cont = (const float*)d_in[1];   // content: (4,3,512,512) f32
    float* loss = (float*)d_out;                 // (4,1,1) f32
    float* ws   = (float*)d_ws;                  // 2048 floats of workspace

    dim3 block(32, 8, 1);
    dim3 grid(8, 64, 4);   // 256 thread-cols x 512 thread-rows x 4 images
    matting_loss_kernel<<<grid, block, 0, stream>>>(outp, cont, ws);
    reduce_kernel<<<dim3(4, 1, 1), dim3(256, 1, 1), 0, stream>>>(ws, loss);
}